// Round 3
// baseline (628.005 us; speedup 1.0000x reference)
//
#include <hip/hip_runtime.h>

// UniversalGRU: 2-layer GRU (B=2048, T=512, D=1, H=64) + FC(64->1).
// R10: WEIGHT-STATIONARY / h-as-B-OPERAND rewrite.
//   A-operand = permuted gate-row weights (constant, in VGPRs),
//   B-operand = hidden state, batch rows as MFMA columns (16 real rows).
// Weight-row permutation Wp[16T+4h'+r] = W[g*64 + 32*(T&2>>1)... ] is chosen
// so lane l's D outputs (rows 4h'+reg, col b=l&15) are EXACTLY the h-columns
// its own next-step B-fragment needs (k in {8h'+j} u {32+8h'+j}).
// => recurrence is fully lane-local: no LDS transpose, no shuffles, no
// bank-conflict-heavy h round-trip. Per block: wave0 = layer0 (self-feeds
// hA in registers, publishes 32B/lane to LDS), wave1 = layer1 skewed by one
// step (consumes hA from LDS, self-feeds hB in registers, never writes).
// 128 blocks x 128 threads, 16 real rows/block, one 2-wave barrier/step.
// R9 lesson: padding-based concurrency doubles DS+MFMA work - instead this
// removes the per-step transpose machinery (R8: ~460 DS-pipe cyc + 8-wave
// barrier drain ~ 1685 cyc/step; here: 4 small DS ops + 2-wave barrier).

#define T_LEN 512
#define BROWS 16
#define XPAD  513
#define LOG2E 1.44269504088896f

typedef float          f32x4 __attribute__((ext_vector_type(4)));
typedef __bf16         bf16x8 __attribute__((ext_vector_type(8)));
typedef unsigned short us8   __attribute__((ext_vector_type(8)));
typedef unsigned int   ui4   __attribute__((ext_vector_type(4)));
typedef unsigned short ushort_t;

__device__ __forceinline__ float bf2f(ushort_t b){
    unsigned int u = ((unsigned int)b) << 16;
    return __uint_as_float(u);
}
__device__ __forceinline__ ushort_t f2bf(float f){
    unsigned int u = __float_as_uint(f);
    u = (u + 0x7FFFu + ((u >> 16) & 1u)) >> 16;   // RNE
    return (ushort_t)u;
}
__device__ __forceinline__ float ld_any(const void* p, int i, bool f32){
    return f32 ? ((const float*)p)[i] : bf2f(((const ushort_t*)p)[i]);
}
__device__ __forceinline__ float exp2_fast(float x){
#if __has_builtin(__builtin_amdgcn_exp2f)
    return __builtin_amdgcn_exp2f(x);          // v_exp_f32 (2^x)
#else
    return __expf(0.6931471805599453f * x);
#endif
}
__device__ __forceinline__ float rcp_fast(float x){
#if __has_builtin(__builtin_amdgcn_rcpf)
    return __builtin_amdgcn_rcpf(x);           // v_rcp_f32
#else
    return __fdividef(1.0f, x);
#endif
}
// sigma(x) with pre-scaled argument t = log2e * x  (3 VALU: exp,add,rcp)
__device__ __forceinline__ float sigm2(float t){
    return rcp_fast(1.0f + exp2_fast(-t));
}
// tanh(y) with pre-scaled argument t = 2*log2e * y (4 VALU)
__device__ __forceinline__ float tanh2(float t){
    return fmaf(-2.0f, rcp_fast(exp2_fast(t) + 1.0f), 1.0f);
}
__device__ __forceinline__ f32x4 mfma16(bf16x8 a, bf16x8 b, f32x4 c){
    return __builtin_amdgcn_mfma_f32_16x16x32_bf16(a, b, c, 0, 0, 0);
}
// packed f32x2 -> bf16x2 (RNE) in one instruction
__device__ __forceinline__ unsigned int cvtpk(float lo, float hi){
    unsigned int r;
    asm("v_cvt_pk_bf16_f32 %0, %1, %2" : "=v"(r) : "v"(lo), "v"(hi));
    return r;
}
// A-fragment: 8 contiguous k's of W[n][k], pre-scaled then bf16-rounded.
__device__ __forceinline__ bf16x8 mk_frag(const void* W, int n, int kb, bool f32, float sc){
    us8 tmp;
    #pragma unroll
    for (int j = 0; j < 8; ++j){
        float v = f32 ? ((const float*)W)[n * 64 + kb + j]
                      : bf2f(((const ushort_t*)W)[n * 64 + kb + j]);
        tmp[j] = f2bf(v * sc);
    }
    return __builtin_bit_cast(bf16x8, tmp);
}

__global__ __launch_bounds__(128, 1) void gru_fused(
    const void* __restrict__ xv,
    const void* __restrict__ Wih0, const void* __restrict__ Whh0,
    const void* __restrict__ bih0, const void* __restrict__ bhh0,
    const void* __restrict__ Wih1, const void* __restrict__ Whh1,
    const void* __restrict__ bih1, const void* __restrict__ bhh1,
    const void* __restrict__ Wfc,  const void* __restrict__ bfc,
    void* __restrict__ outv)
{
    __shared__ float xbuf[BROWS * XPAD];   // staged x, f32, padded stride
    __shared__ ui4   hAx[2][64][2];        // hA(t) handoff, frag-layout, dbuf

    const int tid = threadIdx.x;
    const int wv  = tid >> 6;              // 0 = layer-0 wave, 1 = layer-1 wave
    const int l   = tid & 63;
    const int b   = l & 15;                // batch row (MFMA D column)
    const int hp  = l >> 4;                // k-group h' (MFMA D row block)
    const int am  = l & 15;                // A-operand row this lane loads
    const long row0 = (long)blockIdx.x * BROWS;

    // dtype detection (uniform): fp32 misread as bf16 -> mantissa-noise
    // exponents in even ushort slots; true bf16 never exceeds exp 150.
    bool f32 = false;
    {
        const ushort_t* xs = (const ushort_t*)xv;
        for (int j = 0; j < 64; ++j){
            int e = (xs[2 * j] >> 7) & 0xFF;
            if (e > 150) f32 = true;
        }
    }

    // stage x: 16 rows x 512, both waves cooperate, convert to f32
    if (f32){
        for (int idx = tid; idx < BROWS * (T_LEN / 4); idx += 128){
            const int r = idx >> 7, sg = idx & 127;
            f32x4 v = ((const f32x4*)((const float*)xv + (row0 + r) * T_LEN))[sg];
            #pragma unroll
            for (int j = 0; j < 4; ++j) xbuf[r * XPAD + sg * 4 + j] = v[j];
        }
    } else {
        for (int idx = tid; idx < BROWS * (T_LEN / 8); idx += 128){
            const int r = idx >> 6, sg = idx & 63;
            us8 v = ((const us8*)((const ushort_t*)xv + (row0 + r) * T_LEN))[sg];
            #pragma unroll
            for (int j = 0; j < 8; ++j) xbuf[r * XPAD + sg * 8 + j] = bf2f(v[j]);
        }
    }

    const float gsc0 = LOG2E, gsc2 = 2.0f * LOG2E;

    ui4 z4 = {0u, 0u, 0u, 0u};
    bf16x8 sf0 = __builtin_bit_cast(bf16x8, z4);   // self-feed h frag (k 0..31 slice)
    bf16x8 sf1 = sf0;                              // self-feed h frag (k 32..63 slice)
    f32x4 hS[4] = {{0,0,0,0},{0,0,0,0},{0,0,0,0},{0,0,0,0}};  // f32 h, [tau][reg]

    if (wv == 0){
        // ================= LAYER-0 WAVE =================
        // wh[g][tau][f]: A-frag of permuted Whh0 tile T=4g+tau, k-frag f.
        bf16x8 wh[3][4][2];
        f32x4 cbR[4], cbZ[4], cbNx[4], cbNh[4];    // per-(tau,reg) biases
        f32x4 cwR[4], cwZ[4], cwN[4];              // per-(tau,reg) x-weights
        #pragma unroll
        for (int g = 0; g < 3; ++g){
            const float sc = (g == 2) ? gsc2 : gsc0;
            #pragma unroll
            for (int tau = 0; tau < 4; ++tau){
                const int grow = g * 64 + 32 * (tau >> 1) + 8 * (am >> 2)
                               + 4 * (tau & 1) + (am & 3);
                wh[g][tau][0] = mk_frag(Whh0, grow, 8 * hp,      f32, sc);
                wh[g][tau][1] = mk_frag(Whh0, grow, 32 + 8 * hp, f32, sc);
            }
        }
        #pragma unroll
        for (int tau = 0; tau < 4; ++tau){
            #pragma unroll
            for (int r = 0; r < 4; ++r){
                const int hc = 32 * (tau >> 1) + 8 * hp + 4 * (tau & 1) + r;
                cbR[tau][r]  = (ld_any(bih0, hc, f32) + ld_any(bhh0, hc, f32)) * gsc0;
                cwR[tau][r]  = ld_any(Wih0, hc, f32) * gsc0;
                cbZ[tau][r]  = (ld_any(bih0, 64 + hc, f32) + ld_any(bhh0, 64 + hc, f32)) * gsc0;
                cwZ[tau][r]  = ld_any(Wih0, 64 + hc, f32) * gsc0;
                cbNx[tau][r] = ld_any(bih0, 128 + hc, f32) * gsc2;
                cbNh[tau][r] = ld_any(bhh0, 128 + hc, f32) * gsc2;
                cwN[tau][r]  = ld_any(Wih0, 128 + hc, f32) * gsc2;
            }
        }
        __syncthreads();                           // barrier #0 (x staged)

        for (int t = 0; t < T_LEN; ++t){
            const float xb = xbuf[b * XPAD + t];
            f32x4 aR[4], aZ[4], aN[4], aX[4];
            #pragma unroll
            for (int tau = 0; tau < 4; ++tau){
                #pragma unroll
                for (int r = 0; r < 4; ++r){
                    aR[tau][r] = fmaf(xb, cwR[tau][r], cbR[tau][r]);
                    aZ[tau][r] = fmaf(xb, cwZ[tau][r], cbZ[tau][r]);
                    aX[tau][r] = fmaf(xb, cwN[tau][r], cbNx[tau][r]);  // x-part of n
                }
            }
            #pragma unroll
            for (int tau = 0; tau < 4; ++tau){
                aR[tau] = mfma16(wh[0][tau][0], sf0, aR[tau]);
                aR[tau] = mfma16(wh[0][tau][1], sf1, aR[tau]);
                aZ[tau] = mfma16(wh[1][tau][0], sf0, aZ[tau]);
                aZ[tau] = mfma16(wh[1][tau][1], sf1, aZ[tau]);
                aN[tau] = mfma16(wh[2][tau][0], sf0, cbNh[tau]);   // bias as C-in
                aN[tau] = mfma16(wh[2][tau][1], sf1, aN[tau]);
            }
            unsigned int w[8];
            #pragma unroll
            for (int tau = 0; tau < 4; ++tau){
                #pragma unroll
                for (int r = 0; r < 4; ++r){
                    float rg = sigm2(aR[tau][r]);
                    float zg = sigm2(aZ[tau][r]);
                    float ng = tanh2(aX[tau][r] + rg * aN[tau][r]);
                    hS[tau][r] = ng + zg * (hS[tau][r] - ng);
                }
                w[2 * tau]     = cvtpk(hS[tau][0], hS[tau][1]);
                w[2 * tau + 1] = cvtpk(hS[tau][2], hS[tau][3]);
            }
            ui4 q0 = {w[0], w[1], w[2], w[3]};
            ui4 q1 = {w[4], w[5], w[6], w[7]};
            sf0 = __builtin_bit_cast(bf16x8, q0);  // self-feed: next B-operand
            sf1 = __builtin_bit_cast(bf16x8, q1);
            hAx[t & 1][l][0] = q0;                 // publish hA(t) for layer 1
            hAx[t & 1][l][1] = q1;
            __syncthreads();
        }
        // 513 barriers total; wave exits.
    } else {
        // ================= LAYER-1 WAVE =================
        bf16x8 wi[3][4][2], wh[3][4][2];           // Wih1, Whh1 (permuted)
        f32x4 cbR[4], cbZ[4], cbNx[4], cbNh[4];
        #pragma unroll
        for (int g = 0; g < 3; ++g){
            const float sc = (g == 2) ? gsc2 : gsc0;
            #pragma unroll
            for (int tau = 0; tau < 4; ++tau){
                const int grow = g * 64 + 32 * (tau >> 1) + 8 * (am >> 2)
                               + 4 * (tau & 1) + (am & 3);
                wi[g][tau][0] = mk_frag(Wih1, grow, 8 * hp,      f32, sc);
                wi[g][tau][1] = mk_frag(Wih1, grow, 32 + 8 * hp, f32, sc);
                wh[g][tau][0] = mk_frag(Whh1, grow, 8 * hp,      f32, sc);
                wh[g][tau][1] = mk_frag(Whh1, grow, 32 + 8 * hp, f32, sc);
            }
        }
        #pragma unroll
        for (int tau = 0; tau < 4; ++tau){
            #pragma unroll
            for (int r = 0; r < 4; ++r){
                const int hc = 32 * (tau >> 1) + 8 * hp + 4 * (tau & 1) + r;
                cbR[tau][r]  = (ld_any(bih1, hc, f32) + ld_any(bhh1, hc, f32)) * gsc0;
                cbZ[tau][r]  = (ld_any(bih1, 64 + hc, f32) + ld_any(bhh1, 64 + hc, f32)) * gsc0;
                cbNx[tau][r] = ld_any(bih1, 128 + hc, f32) * gsc2;
                cbNh[tau][r] = ld_any(bhh1, 128 + hc, f32) * gsc2;
            }
        }
        __syncthreads();                           // barrier #0 (x staged)

        // iteration t computes hB(t-1); t=T_LEN is the epilogue step.
        for (int t = 0; t <= T_LEN; ++t){
            if (t > 0){
                ui4 q0 = hAx[(t - 1) & 1][l][0];
                ui4 q1 = hAx[(t - 1) & 1][l][1];
                bf16x8 gA0 = __builtin_bit_cast(bf16x8, q0);
                bf16x8 gA1 = __builtin_bit_cast(bf16x8, q1);
                f32x4 aR[4], aZ[4], aX[4], aN[4];
                #pragma unroll
                for (int tau = 0; tau < 4; ++tau){
                    aR[tau] = mfma16(wi[0][tau][0], gA0, cbR[tau]);
                    aR[tau] = mfma16(wi[0][tau][1], gA1, aR[tau]);
                    aR[tau] = mfma16(wh[0][tau][0], sf0, aR[tau]);
                    aR[tau] = mfma16(wh[0][tau][1], sf1, aR[tau]);
                    aZ[tau] = mfma16(wi[1][tau][0], gA0, cbZ[tau]);
                    aZ[tau] = mfma16(wi[1][tau][1], gA1, aZ[tau]);
                    aZ[tau] = mfma16(wh[1][tau][0], sf0, aZ[tau]);
                    aZ[tau] = mfma16(wh[1][tau][1], sf1, aZ[tau]);
                    aX[tau] = mfma16(wi[2][tau][0], gA0, cbNx[tau]);  // x-part of n
                    aX[tau] = mfma16(wi[2][tau][1], gA1, aX[tau]);
                    aN[tau] = mfma16(wh[2][tau][0], sf0, cbNh[tau]);  // h-part of n
                    aN[tau] = mfma16(wh[2][tau][1], sf1, aN[tau]);
                }
                unsigned int w[8];
                #pragma unroll
                for (int tau = 0; tau < 4; ++tau){
                    #pragma unroll
                    for (int r = 0; r < 4; ++r){
                        float rg = sigm2(aR[tau][r]);
                        float zg = sigm2(aZ[tau][r]);
                        float ng = tanh2(aX[tau][r] + rg * aN[tau][r]);
                        hS[tau][r] = ng + zg * (hS[tau][r] - ng);
                    }
                    w[2 * tau]     = cvtpk(hS[tau][0], hS[tau][1]);
                    w[2 * tau + 1] = cvtpk(hS[tau][2], hS[tau][3]);
                }
                ui4 p0 = {w[0], w[1], w[2], w[3]};
                ui4 p1 = {w[4], w[5], w[6], w[7]};
                sf0 = __builtin_bit_cast(bf16x8, p0);   // hB self-feed only
                sf1 = __builtin_bit_cast(bf16x8, p1);
            }
            if (t < T_LEN) __syncthreads();        // 512 in-loop barriers
        }

        // FC: out[b] = bfc + sum_h Wfc[h] * hB511[h][b]; lane holds 16 h-terms
        float part = 0.0f;
        #pragma unroll
        for (int tau = 0; tau < 4; ++tau){
            #pragma unroll
            for (int r = 0; r < 4; ++r){
                const int hc = 32 * (tau >> 1) + 8 * hp + 4 * (tau & 1) + r;
                part = fmaf(ld_any(Wfc, hc, f32), hS[tau][r], part);
            }
        }
        part += __shfl_xor(part, 16);
        part += __shfl_xor(part, 32);
        if (l < 16){
            float s = part + ld_any(bfc, 0, f32);
            if (f32) ((float*)outv)[row0 + b] = s;
            else     ((ushort_t*)outv)[row0 + b] = f2bf(s);
        }
    }
}

extern "C" void kernel_launch(void* const* d_in, const int* in_sizes, int n_in,
                              void* d_out, int out_size, void* d_ws, size_t ws_size,
                              hipStream_t stream)
{
    (void)in_sizes; (void)n_in; (void)d_ws; (void)ws_size;
    const int B = out_size;               // O = 1 -> out_size == batch
    const int nblk = B / BROWS;           // 2048/16 = 128 blocks, 2 waves each
    gru_fused<<<nblk, 128, 0, stream>>>(
        d_in[0],
        d_in[1], d_in[2], d_in[3], d_in[4],
        d_in[5], d_in[6], d_in[7], d_in[8],
        d_in[9], d_in[10],
        d_out);
}

// Round 4
// 423.400 us; speedup vs baseline: 1.4832x; 1.4832x over previous
//
#include <hip/hip_runtime.h>

// UniversalGRU: 2-layer GRU (B=2048, T=512, D=1, H=64) + FC(64->1).
// R11 = R10 dataflow (h-as-B-operand, weight-stationary, lane-local
// recurrence -- verified correct in R10) with the two R10 failure modes
// fixed:
//  1) SPILLS: R10's L1 wave held 48 weight frags (192 VGPR) -> VGPR=256 +
//     5.6 GB scratch WRITE_SIZE. R11 splits each layer across TWO waves by
//     tau-pair (tau in {0,1} / {2,3}), so each wave holds 12-24 frags
//     (48-96 VGPR), total ~190 -> no spill.
//  2) 1 wave/SIMD: 4 waves/block now cover all 4 SIMDs of each of the 128
//     active CUs.
// Self-feed splits cleanly: the tau{0,1} wave computes exactly the sf0
// (k 0..31) h-slice its own B-frag needs; tau{2,3} computes sf1. Each wave
// keeps its half in registers and swaps the other half through a 16B/lane
// frag-layout LDS buffer (the same channel that hands hA to the L1 waves).
// One 4-wave barrier per step. 128 blocks x 256 threads.

#define T_LEN 512
#define BROWS 16
#define XPAD  513
#define LOG2E 1.44269504088896f

typedef float          f32x4 __attribute__((ext_vector_type(4)));
typedef __bf16         bf16x8 __attribute__((ext_vector_type(8)));
typedef unsigned short us8   __attribute__((ext_vector_type(8)));
typedef unsigned int   ui4   __attribute__((ext_vector_type(4)));
typedef unsigned short ushort_t;

__device__ __forceinline__ float bf2f(ushort_t b){
    unsigned int u = ((unsigned int)b) << 16;
    return __uint_as_float(u);
}
__device__ __forceinline__ ushort_t f2bf(float f){
    unsigned int u = __float_as_uint(f);
    u = (u + 0x7FFFu + ((u >> 16) & 1u)) >> 16;   // RNE
    return (ushort_t)u;
}
__device__ __forceinline__ float ld_any(const void* p, int i, bool f32){
    return f32 ? ((const float*)p)[i] : bf2f(((const ushort_t*)p)[i]);
}
__device__ __forceinline__ float exp2_fast(float x){
#if __has_builtin(__builtin_amdgcn_exp2f)
    return __builtin_amdgcn_exp2f(x);          // v_exp_f32 (2^x)
#else
    return __expf(0.6931471805599453f * x);
#endif
}
__device__ __forceinline__ float rcp_fast(float x){
#if __has_builtin(__builtin_amdgcn_rcpf)
    return __builtin_amdgcn_rcpf(x);           // v_rcp_f32
#else
    return __fdividef(1.0f, x);
#endif
}
// sigma(x) with pre-scaled argument t = log2e * x  (exp,add,rcp)
__device__ __forceinline__ float sigm2(float t){
    return rcp_fast(1.0f + exp2_fast(-t));
}
// tanh(y) with pre-scaled argument t = 2*log2e * y
__device__ __forceinline__ float tanh2(float t){
    return fmaf(-2.0f, rcp_fast(exp2_fast(t) + 1.0f), 1.0f);
}
__device__ __forceinline__ f32x4 mfma16(bf16x8 a, bf16x8 b, f32x4 c){
    return __builtin_amdgcn_mfma_f32_16x16x32_bf16(a, b, c, 0, 0, 0);
}
// packed f32x2 -> bf16x2 (RNE) in one instruction
__device__ __forceinline__ unsigned int cvtpk(float lo, float hi){
    unsigned int r;
    asm("v_cvt_pk_bf16_f32 %0, %1, %2" : "=v"(r) : "v"(lo), "v"(hi));
    return r;
}
// A-fragment: 8 contiguous k's of W[n][k], pre-scaled then bf16-rounded.
__device__ __forceinline__ bf16x8 mk_frag(const void* W, int n, int kb, bool f32, float sc){
    us8 tmp;
    #pragma unroll
    for (int j = 0; j < 8; ++j){
        float v = f32 ? ((const float*)W)[n * 64 + kb + j]
                      : bf2f(((const ushort_t*)W)[n * 64 + kb + j]);
        tmp[j] = f2bf(v * sc);
    }
    return __builtin_bit_cast(bf16x8, tmp);
}

__global__ __launch_bounds__(256, 1) void gru_fused(
    const void* __restrict__ xv,
    const void* __restrict__ Wih0, const void* __restrict__ Whh0,
    const void* __restrict__ bih0, const void* __restrict__ bhh0,
    const void* __restrict__ Wih1, const void* __restrict__ Whh1,
    const void* __restrict__ bih1, const void* __restrict__ bhh1,
    const void* __restrict__ Wfc,  const void* __restrict__ bfc,
    void* __restrict__ outv)
{
    __shared__ float xbuf[BROWS * XPAD];   // staged x, f32, padded stride
    // h exchange, frag layout, double-buffered. which: 0=hA half0 (k0..31),
    // 1=hA half1 (k32..63), 2=hB half0, 3=hB half1.
    __shared__ ui4   hX[2][4][64];
    __shared__ float fcb[2][16];           // FC cross-wave partials

    const int tid  = threadIdx.x;
    const int wv   = tid >> 6;             // 0..3
    const int layer = wv >> 1;             // 0 = GRU0, 1 = GRU1
    const int half  = wv & 1;              // tau-pair: {0,1} or {2,3}
    const int l   = tid & 63;
    const int b   = l & 15;                // batch row (MFMA D column)
    const int hp  = l >> 4;                // k-group (MFMA D row block)
    const int am  = l & 15;                // A-operand row this lane loads
    const long row0 = (long)blockIdx.x * BROWS;

    // dtype detection (uniform): fp32 misread as bf16 -> mantissa-noise
    // exponents in even ushort slots; true bf16 never exceeds exp 150.
    bool f32 = false;
    {
        const ushort_t* xs = (const ushort_t*)xv;
        for (int j = 0; j < 64; ++j){
            int e = (xs[2 * j] >> 7) & 0xFF;
            if (e > 150) f32 = true;
        }
    }

    // zero exchange buffers (h(-1) = 0, h(-2) = 0)
    {
        ui4 z = {0u, 0u, 0u, 0u};
        ui4* ph = &hX[0][0][0];
        for (int k = tid; k < 2 * 4 * 64; k += 256) ph[k] = z;
    }
    // stage x: 16 rows x 512, all 4 waves cooperate, convert to f32
    if (f32){
        for (int idx = tid; idx < BROWS * (T_LEN / 4); idx += 256){
            const int r = idx >> 7, sg = idx & 127;
            f32x4 v = ((const f32x4*)((const float*)xv + (row0 + r) * T_LEN))[sg];
            #pragma unroll
            for (int j = 0; j < 4; ++j) xbuf[r * XPAD + sg * 4 + j] = v[j];
        }
    } else {
        for (int idx = tid; idx < BROWS * (T_LEN / 8); idx += 256){
            const int r = idx >> 6, sg = idx & 63;
            us8 v = ((const us8*)((const ushort_t*)xv + (row0 + r) * T_LEN))[sg];
            #pragma unroll
            for (int j = 0; j < 8; ++j) xbuf[r * XPAD + sg * 8 + j] = bf2f(v[j]);
        }
    }

    const float gsc0 = LOG2E, gsc2 = 2.0f * LOG2E;

    // ---- weight / bias setup (per wave role) ----
    // tau = 2*half + s, s in {0,1}. Permuted gate row:
    //   grow = g*64 + 32*half + 8*(am>>2) + 4*s + (am&3)
    // Lane's D outputs: h-col hc = 32*half + 8*hp + 4*s + r  (s,r = 0..3/0..3)
    bf16x8 wA[3][2][2];                    // L0: Whh0. L1: Wih1.
    bf16x8 wH[3][2][2];                    // L1 only: Whh1.
    f32x4 cbR[2], cbZ[2], cbNx[2], cbNh[2];
    f32x4 cwR[2], cwZ[2], cwN[2];          // L0 only: scalar-x weights
    const void* Wihp = layer ? Wih1 : Wih0;
    const void* Whhp = layer ? Whh1 : Whh0;
    const void* bihp = layer ? bih1 : bih0;
    const void* bhhp = layer ? bhh1 : bhh0;
    #pragma unroll
    for (int g = 0; g < 3; ++g){
        const float sc = (g == 2) ? gsc2 : gsc0;
        #pragma unroll
        for (int s = 0; s < 2; ++s){
            const int grow = g * 64 + 32 * half + 8 * (am >> 2) + 4 * s + (am & 3);
            if (layer == 0){
                wA[g][s][0] = mk_frag(Whhp, grow, 8 * hp,      f32, sc);
                wA[g][s][1] = mk_frag(Whhp, grow, 32 + 8 * hp, f32, sc);
            } else {
                wA[g][s][0] = mk_frag(Wihp, grow, 8 * hp,      f32, sc);
                wA[g][s][1] = mk_frag(Wihp, grow, 32 + 8 * hp, f32, sc);
                wH[g][s][0] = mk_frag(Whhp, grow, 8 * hp,      f32, sc);
                wH[g][s][1] = mk_frag(Whhp, grow, 32 + 8 * hp, f32, sc);
            }
        }
    }
    #pragma unroll
    for (int s = 0; s < 2; ++s){
        #pragma unroll
        for (int r = 0; r < 4; ++r){
            const int hc = 32 * half + 8 * hp + 4 * s + r;
            cbR[s][r]  = (ld_any(bihp, hc, f32)      + ld_any(bhhp, hc, f32))      * gsc0;
            cbZ[s][r]  = (ld_any(bihp, 64 + hc, f32) + ld_any(bhhp, 64 + hc, f32)) * gsc0;
            cbNx[s][r] = ld_any(bihp, 128 + hc, f32) * gsc2;
            cbNh[s][r] = ld_any(bhhp, 128 + hc, f32) * gsc2;
            if (layer == 0){
                cwR[s][r] = ld_any(Wih0, hc, f32)       * gsc0;
                cwZ[s][r] = ld_any(Wih0, 64 + hc, f32)  * gsc0;
                cwN[s][r] = ld_any(Wih0, 128 + hc, f32) * gsc2;
            }
        }
    }

    ui4 z4 = {0u, 0u, 0u, 0u};
    bf16x8 sf_own = __builtin_bit_cast(bf16x8, z4);  // own h half (8 bf16)
    f32x4 hS[2] = {{0,0,0,0},{0,0,0,0}};             // f32 h, [s][r]

    __syncthreads();

    for (int t = 0; t < T_LEN; ++t){
        if (layer == 0){
            // ---- layer 0, step t: hA(t) = GRU0(x(t), hA(t-1)) ----
            const int p  = t & 1;              // write parity
            const int pr = p ^ 1;              // read parity (t-1)
            ui4 qo = hX[pr][1 - half][l];      // other hA half
            bf16x8 sfO = __builtin_bit_cast(bf16x8, qo);
            bf16x8 B0 = half ? sfO : sf_own;   // k 0..31 slice
            bf16x8 B1 = half ? sf_own : sfO;   // k 32..63 slice
            const float xb = xbuf[b * XPAD + t];
            f32x4 aR[2], aZ[2], aX[2], aN[2];
            #pragma unroll
            for (int s = 0; s < 2; ++s){
                #pragma unroll
                for (int r = 0; r < 4; ++r){
                    aR[s][r] = fmaf(xb, cwR[s][r], cbR[s][r]);
                    aZ[s][r] = fmaf(xb, cwZ[s][r], cbZ[s][r]);
                    aX[s][r] = fmaf(xb, cwN[s][r], cbNx[s][r]);
                }
            }
            #pragma unroll
            for (int s = 0; s < 2; ++s){
                aR[s] = mfma16(wA[0][s][0], B0, aR[s]);
                aR[s] = mfma16(wA[0][s][1], B1, aR[s]);
                aZ[s] = mfma16(wA[1][s][0], B0, aZ[s]);
                aZ[s] = mfma16(wA[1][s][1], B1, aZ[s]);
                aN[s] = mfma16(wA[2][s][0], B0, cbNh[s]);   // bias as C-in
                aN[s] = mfma16(wA[2][s][1], B1, aN[s]);
            }
            unsigned int w[4];
            #pragma unroll
            for (int s = 0; s < 2; ++s){
                #pragma unroll
                for (int r = 0; r < 4; ++r){
                    float rg = sigm2(aR[s][r]);
                    float zg = sigm2(aZ[s][r]);
                    float ng = tanh2(aX[s][r] + rg * aN[s][r]);
                    hS[s][r] = ng + zg * (hS[s][r] - ng);
                }
                w[2 * s]     = cvtpk(hS[s][0], hS[s][1]);
                w[2 * s + 1] = cvtpk(hS[s][2], hS[s][3]);
            }
            ui4 own = {w[0], w[1], w[2], w[3]};
            sf_own = __builtin_bit_cast(bf16x8, own);
            hX[p][half][l] = own;              // publish hA(t) half
        } else if (t > 0){
            // ---- layer 1, step t-1: hB(t-1) = GRU1(hA(t-1), hB(t-2)) ----
            const int pa = (t - 1) & 1;        // hA read parity & hB write parity
            const int pb = pa ^ 1;             // hB read parity (t-2)
            ui4 qa0 = hX[pa][0][l];
            ui4 qa1 = hX[pa][1][l];
            ui4 qbo = hX[pb][2 + (1 - half)][l];
            bf16x8 gA0 = __builtin_bit_cast(bf16x8, qa0);
            bf16x8 gA1 = __builtin_bit_cast(bf16x8, qa1);
            bf16x8 sfO = __builtin_bit_cast(bf16x8, qbo);
            bf16x8 B0 = half ? sfO : sf_own;
            bf16x8 B1 = half ? sf_own : sfO;
            f32x4 aR[2], aZ[2], aX[2], aN[2];
            #pragma unroll
            for (int s = 0; s < 2; ++s){
                aR[s] = mfma16(wA[0][s][0], gA0, cbR[s]);
                aR[s] = mfma16(wA[0][s][1], gA1, aR[s]);
                aR[s] = mfma16(wH[0][s][0], B0,  aR[s]);
                aR[s] = mfma16(wH[0][s][1], B1,  aR[s]);
                aZ[s] = mfma16(wA[1][s][0], gA0, cbZ[s]);
                aZ[s] = mfma16(wA[1][s][1], gA1, aZ[s]);
                aZ[s] = mfma16(wH[1][s][0], B0,  aZ[s]);
                aZ[s] = mfma16(wH[1][s][1], B1,  aZ[s]);
                aX[s] = mfma16(wA[2][s][0], gA0, cbNx[s]);  // x-part of n
                aX[s] = mfma16(wA[2][s][1], gA1, aX[s]);
                aN[s] = mfma16(wH[2][s][0], B0,  cbNh[s]);  // h-part of n
                aN[s] = mfma16(wH[2][s][1], B1,  aN[s]);
            }
            unsigned int w[4];
            #pragma unroll
            for (int s = 0; s < 2; ++s){
                #pragma unroll
                for (int r = 0; r < 4; ++r){
                    float rg = sigm2(aR[s][r]);
                    float zg = sigm2(aZ[s][r]);
                    float ng = tanh2(aX[s][r] + rg * aN[s][r]);
                    hS[s][r] = ng + zg * (hS[s][r] - ng);
                }
                w[2 * s]     = cvtpk(hS[s][0], hS[s][1]);
                w[2 * s + 1] = cvtpk(hS[s][2], hS[s][3]);
            }
            ui4 own = {w[0], w[1], w[2], w[3]};
            sf_own = __builtin_bit_cast(bf16x8, own);
            hX[pa][2 + half][l] = own;         // publish hB(t-1) half
        }
        __syncthreads();
    }

    // Epilogue: L1 waves compute hB(511) from hA(511) and hB(510), then FC.
    if (layer == 1){
        const int pa = (T_LEN - 1) & 1;        // = 1
        const int pb = pa ^ 1;                 // = 0
        ui4 qa0 = hX[pa][0][l];
        ui4 qa1 = hX[pa][1][l];
        ui4 qbo = hX[pb][2 + (1 - half)][l];
        bf16x8 gA0 = __builtin_bit_cast(bf16x8, qa0);
        bf16x8 gA1 = __builtin_bit_cast(bf16x8, qa1);
        bf16x8 sfO = __builtin_bit_cast(bf16x8, qbo);
        bf16x8 B0 = half ? sfO : sf_own;
        bf16x8 B1 = half ? sf_own : sfO;
        f32x4 aR[2], aZ[2], aX[2], aN[2];
        #pragma unroll
        for (int s = 0; s < 2; ++s){
            aR[s] = mfma16(wA[0][s][0], gA0, cbR[s]);
            aR[s] = mfma16(wA[0][s][1], gA1, aR[s]);
            aR[s] = mfma16(wH[0][s][0], B0,  aR[s]);
            aR[s] = mfma16(wH[0][s][1], B1,  aR[s]);
            aZ[s] = mfma16(wA[1][s][0], gA0, cbZ[s]);
            aZ[s] = mfma16(wA[1][s][1], gA1, aZ[s]);
            aZ[s] = mfma16(wH[1][s][0], B0,  aZ[s]);
            aZ[s] = mfma16(wH[1][s][1], B1,  aZ[s]);
            aX[s] = mfma16(wA[2][s][0], gA0, cbNx[s]);
            aX[s] = mfma16(wA[2][s][1], gA1, aX[s]);
            aN[s] = mfma16(wH[2][s][0], B0,  cbNh[s]);
            aN[s] = mfma16(wH[2][s][1], B1,  aN[s]);
        }
        float part = 0.0f;
        #pragma unroll
        for (int s = 0; s < 2; ++s){
            #pragma unroll
            for (int r = 0; r < 4; ++r){
                float rg = sigm2(aR[s][r]);
                float zg = sigm2(aZ[s][r]);
                float ng = tanh2(aX[s][r] + rg * aN[s][r]);
                float hf = ng + zg * (hS[s][r] - ng);
                const int hc = 32 * half + 8 * hp + 4 * s + r;
                part = fmaf(ld_any(Wfc, hc, f32), hf, part);
            }
        }
        part += __shfl_xor(part, 16);          // reduce across hp
        part += __shfl_xor(part, 32);
        if (l < 16) fcb[half][b] = part;
    }
    __syncthreads();

    if (wv == 2 && l < 16){
        float s = fcb[0][b] + fcb[1][b] + ld_any(bfc, 0, f32);
        if (f32) ((float*)outv)[row0 + b] = s;
        else     ((ushort_t*)outv)[row0 + b] = f2bf(s);
    }
}

extern "C" void kernel_launch(void* const* d_in, const int* in_sizes, int n_in,
                              void* d_out, int out_size, void* d_ws, size_t ws_size,
                              hipStream_t stream)
{
    (void)in_sizes; (void)n_in; (void)d_ws; (void)ws_size;
    const int B = out_size;               // O = 1 -> out_size == batch
    const int nblk = B / BROWS;           // 2048/16 = 128 blocks, 4 waves each
    gru_fused<<<nblk, 256, 0, stream>>>(
        d_in[0],
        d_in[1], d_in[2], d_in[3], d_in[4],
        d_in[5], d_in[6], d_in[7], d_in[8],
        d_in[9], d_in[10],
        d_out);
}

// Round 5
// 348.111 us; speedup vs baseline: 1.8040x; 1.2163x over previous
//
#include <hip/hip_runtime.h>

// UniversalGRU: 2-layer GRU (B=2048, T=512, D=1, H=64) + FC(64->1).
// R12 = R11 dataflow (h-as-B-operand, weight-stationary, lane-local
// recurrence, no LDS transpose) with the occupancy shape fixed:
// TAU-SINGLE split -- each layer spread over FOUR waves (one 16x16 weight
// tile each) instead of two. 8 waves/block x 128 blocks = 2 waves/SIMD
// (an L0+L1 pair per SIMD, at different phases of the skewed pipeline).
// R11 counters: Occ 5.8% (1 wave/SIMD), VALU 26%, step = 1815 cyc of
// which ~1200 was exposed latency (ds_read ~120cyc, dep-MFMA chain,
// exp->rcp chains, 4-wave barrier) with nothing co-resident to fill it.
// R12 halves per-wave issue (L1: 12 MFMA + 24 trans; L0: 6 MFMA + 24
// trans) and doubles waves/SIMD so the two chains interleave.
// h exchange: each wave publishes its quarter (ui2 = 4 bf16, frag layout)
// to LDS; consumers reassemble B-frags from 4 stride-1 ds_read_b64 --
// conflict-free, no shuffles. One 8-wave barrier per step.

#define T_LEN 512
#define BROWS 16
#define XPAD  513
#define LOG2E 1.44269504088896f

typedef float          f32x4 __attribute__((ext_vector_type(4)));
typedef __bf16         bf16x8 __attribute__((ext_vector_type(8)));
typedef unsigned short us8   __attribute__((ext_vector_type(8)));
typedef unsigned int   ui4   __attribute__((ext_vector_type(4)));
typedef unsigned int   ui2   __attribute__((ext_vector_type(2)));
typedef unsigned short ushort_t;

__device__ __forceinline__ float bf2f(ushort_t b){
    unsigned int u = ((unsigned int)b) << 16;
    return __uint_as_float(u);
}
__device__ __forceinline__ ushort_t f2bf(float f){
    unsigned int u = __float_as_uint(f);
    u = (u + 0x7FFFu + ((u >> 16) & 1u)) >> 16;   // RNE
    return (ushort_t)u;
}
__device__ __forceinline__ float ld_any(const void* p, int i, bool f32){
    return f32 ? ((const float*)p)[i] : bf2f(((const ushort_t*)p)[i]);
}
__device__ __forceinline__ float exp2_fast(float x){
#if __has_builtin(__builtin_amdgcn_exp2f)
    return __builtin_amdgcn_exp2f(x);          // v_exp_f32 (2^x)
#else
    return __expf(0.6931471805599453f * x);
#endif
}
__device__ __forceinline__ float rcp_fast(float x){
#if __has_builtin(__builtin_amdgcn_rcpf)
    return __builtin_amdgcn_rcpf(x);           // v_rcp_f32
#else
    return __fdividef(1.0f, x);
#endif
}
// sigma(x) with pre-scaled argument t = log2e * x
__device__ __forceinline__ float sigm2(float t){
    return rcp_fast(1.0f + exp2_fast(-t));
}
// tanh(y) with pre-scaled argument t = 2*log2e * y
__device__ __forceinline__ float tanh2(float t){
    return fmaf(-2.0f, rcp_fast(exp2_fast(t) + 1.0f), 1.0f);
}
__device__ __forceinline__ f32x4 mfma16(bf16x8 a, bf16x8 b, f32x4 c){
    return __builtin_amdgcn_mfma_f32_16x16x32_bf16(a, b, c, 0, 0, 0);
}
// packed f32x2 -> bf16x2 (RNE) in one instruction
__device__ __forceinline__ unsigned int cvtpk(float lo, float hi){
    unsigned int r;
    asm("v_cvt_pk_bf16_f32 %0, %1, %2" : "=v"(r) : "v"(lo), "v"(hi));
    return r;
}
// A-fragment: 8 contiguous k's of W[n][k], pre-scaled then bf16-rounded.
__device__ __forceinline__ bf16x8 mk_frag(const void* W, int n, int kb, bool f32, float sc){
    us8 tmp;
    #pragma unroll
    for (int j = 0; j < 8; ++j){
        float v = f32 ? ((const float*)W)[n * 64 + kb + j]
                      : bf2f(((const ushort_t*)W)[n * 64 + kb + j]);
        tmp[j] = f2bf(v * sc);
    }
    return __builtin_bit_cast(bf16x8, tmp);
}

__global__ __launch_bounds__(512, 2) void gru_fused(
    const void* __restrict__ xv,
    const void* __restrict__ Wih0, const void* __restrict__ Whh0,
    const void* __restrict__ bih0, const void* __restrict__ bhh0,
    const void* __restrict__ Wih1, const void* __restrict__ Whh1,
    const void* __restrict__ bih1, const void* __restrict__ bhh1,
    const void* __restrict__ Wfc,  const void* __restrict__ bfc,
    void* __restrict__ outv)
{
    __shared__ float xbuf[BROWS * XPAD];   // staged x, f32, padded stride
    // h exchange: [parity][quarter tau][lane], ui2 = 4 bf16 in frag layout.
    __shared__ ui2   hAq[2][4][64];
    __shared__ ui2   hBq[2][4][64];
    __shared__ float fcb[4][16];           // FC cross-wave partials

    const int tid   = threadIdx.x;
    const int wv    = tid >> 6;            // 0..7
    const int layer = wv >> 2;             // 0 = GRU0 waves, 1 = GRU1 waves
    const int tau   = wv & 3;              // weight tile this wave owns
    const int l  = tid & 63;
    const int b  = l & 15;                 // batch row (MFMA D column)
    const int hp = l >> 4;                 // k-group (MFMA D row block)
    const int am = l & 15;                 // A-operand row this lane loads
    const long row0 = (long)blockIdx.x * BROWS;

    // dtype detection (uniform): fp32 misread as bf16 -> mantissa-noise
    // exponents in even ushort slots; true bf16 never exceeds exp 150.
    bool f32 = false;
    {
        const ushort_t* xs = (const ushort_t*)xv;
        for (int j = 0; j < 64; ++j){
            int e = (xs[2 * j] >> 7) & 0xFF;
            if (e > 150) f32 = true;
        }
    }

    // zero exchange buffers (h(-1) = 0, h(-2) = 0; both parities for safety)
    {
        ui2 z = {0u, 0u};
        ui2* pa = &hAq[0][0][0];
        ui2* pb = &hBq[0][0][0];
        for (int k = tid; k < 2 * 4 * 64; k += 512){ pa[k] = z; pb[k] = z; }
    }
    // stage x: 16 rows x 512, all 8 waves cooperate, convert to f32
    if (f32){
        for (int idx = tid; idx < BROWS * (T_LEN / 4); idx += 512){
            const int r = idx >> 7, sg = idx & 127;
            f32x4 v = ((const f32x4*)((const float*)xv + (row0 + r) * T_LEN))[sg];
            #pragma unroll
            for (int j = 0; j < 4; ++j) xbuf[r * XPAD + sg * 4 + j] = v[j];
        }
    } else {
        for (int idx = tid; idx < BROWS * (T_LEN / 8); idx += 512){
            const int r = idx >> 6, sg = idx & 63;
            us8 v = ((const us8*)((const ushort_t*)xv + (row0 + r) * T_LEN))[sg];
            #pragma unroll
            for (int j = 0; j < 8; ++j) xbuf[r * XPAD + sg * 8 + j] = bf2f(v[j]);
        }
    }

    const float gsc0 = LOG2E, gsc2 = 2.0f * LOG2E;

    // ---- weight / bias setup (per wave role) ----
    // Permuted gate row for tile tau:
    //   grow(g) = g*64 + 32*(tau>>1) + 8*(am>>2) + 4*(tau&1) + (am&3)
    // Lane's D outputs land at h-col hc(r) = hb0 + r,
    //   hb0 = 32*(tau>>1) + 8*hp + 4*(tau&1),
    // which is exactly the ui2 quarter this wave publishes.
    bf16x8 wA[3][2];                       // L0: Whh0. L1: Wih1.
    bf16x8 wH[3][2];                       // L1 only: Whh1.
    f32x4 cbR, cbZ, cbNx, cbNh;
    f32x4 cwR, cwZ, cwN;                   // L0 only: scalar-x weights
    const void* Wihp = layer ? Wih1 : Wih0;
    const void* Whhp = layer ? Whh1 : Whh0;
    const void* bihp = layer ? bih1 : bih0;
    const void* bhhp = layer ? bhh1 : bhh0;
    const int hb0 = 32 * (tau >> 1) + 8 * hp + 4 * (tau & 1);
    #pragma unroll
    for (int g = 0; g < 3; ++g){
        const float sc = (g == 2) ? gsc2 : gsc0;
        const int grow = g * 64 + 32 * (tau >> 1) + 8 * (am >> 2) + 4 * (tau & 1) + (am & 3);
        if (layer == 0){
            wA[g][0] = mk_frag(Whhp, grow, 8 * hp,      f32, sc);
            wA[g][1] = mk_frag(Whhp, grow, 32 + 8 * hp, f32, sc);
        } else {
            wA[g][0] = mk_frag(Wihp, grow, 8 * hp,      f32, sc);
            wA[g][1] = mk_frag(Wihp, grow, 32 + 8 * hp, f32, sc);
            wH[g][0] = mk_frag(Whhp, grow, 8 * hp,      f32, sc);
            wH[g][1] = mk_frag(Whhp, grow, 32 + 8 * hp, f32, sc);
        }
    }
    #pragma unroll
    for (int r = 0; r < 4; ++r){
        const int hc = hb0 + r;
        cbR[r]  = (ld_any(bihp, hc, f32)      + ld_any(bhhp, hc, f32))      * gsc0;
        cbZ[r]  = (ld_any(bihp, 64 + hc, f32) + ld_any(bhhp, 64 + hc, f32)) * gsc0;
        cbNx[r] = ld_any(bihp, 128 + hc, f32) * gsc2;
        cbNh[r] = ld_any(bhhp, 128 + hc, f32) * gsc2;
        if (layer == 0){
            cwR[r] = ld_any(Wih0, hc, f32)       * gsc0;
            cwZ[r] = ld_any(Wih0, 64 + hc, f32)  * gsc0;
            cwN[r] = ld_any(Wih0, 128 + hc, f32) * gsc2;
        }
    }

    f32x4 hS = {0.f, 0.f, 0.f, 0.f};       // f32-carried h, this wave's quarter

    __syncthreads();

    for (int t = 0; t < T_LEN; ++t){
        if (layer == 0){
            // ---- layer 0, step t: hA(t) = GRU0(x(t), hA(t-1)) ----
            const int p = t & 1, pr = p ^ 1;
            ui2 q0 = hAq[pr][0][l], q1 = hAq[pr][1][l];
            ui2 q2 = hAq[pr][2][l], q3 = hAq[pr][3][l];
            ui4 u0 = {q0[0], q0[1], q1[0], q1[1]};
            ui4 u1 = {q2[0], q2[1], q3[0], q3[1]};
            bf16x8 B0 = __builtin_bit_cast(bf16x8, u0);   // k 8hp..8hp+7
            bf16x8 B1 = __builtin_bit_cast(bf16x8, u1);   // k 32+8hp..+7
            const float xb = xbuf[b * XPAD + t];
            f32x4 aR, aZ, aX, aN;
            #pragma unroll
            for (int r = 0; r < 4; ++r){
                aR[r] = fmaf(xb, cwR[r], cbR[r]);
                aZ[r] = fmaf(xb, cwZ[r], cbZ[r]);
                aX[r] = fmaf(xb, cwN[r], cbNx[r]);
            }
            aR = mfma16(wA[0][0], B0, aR); aR = mfma16(wA[0][1], B1, aR);
            aZ = mfma16(wA[1][0], B0, aZ); aZ = mfma16(wA[1][1], B1, aZ);
            aN = mfma16(wA[2][0], B0, cbNh); aN = mfma16(wA[2][1], B1, aN);
            #pragma unroll
            for (int r = 0; r < 4; ++r){
                float rg = sigm2(aR[r]);
                float zg = sigm2(aZ[r]);
                float ng = tanh2(aX[r] + rg * aN[r]);
                hS[r] = ng + zg * (hS[r] - ng);
            }
            ui2 own = { cvtpk(hS[0], hS[1]), cvtpk(hS[2], hS[3]) };
            hAq[p][tau][l] = own;
        } else if (t > 0){
            // ---- layer 1, step t-1: hB(t-1) = GRU1(hA(t-1), hB(t-2)) ----
            const int pa = (t - 1) & 1, pb = pa ^ 1;
            ui2 a0 = hAq[pa][0][l], a1 = hAq[pa][1][l];
            ui2 a2 = hAq[pa][2][l], a3 = hAq[pa][3][l];
            ui2 c0 = hBq[pb][0][l], c1 = hBq[pb][1][l];
            ui2 c2 = hBq[pb][2][l], c3 = hBq[pb][3][l];
            ui4 ua0 = {a0[0], a0[1], a1[0], a1[1]};
            ui4 ua1 = {a2[0], a2[1], a3[0], a3[1]};
            ui4 ub0 = {c0[0], c0[1], c1[0], c1[1]};
            ui4 ub1 = {c2[0], c2[1], c3[0], c3[1]};
            bf16x8 gA0 = __builtin_bit_cast(bf16x8, ua0);
            bf16x8 gA1 = __builtin_bit_cast(bf16x8, ua1);
            bf16x8 B0  = __builtin_bit_cast(bf16x8, ub0);
            bf16x8 B1  = __builtin_bit_cast(bf16x8, ub1);
            f32x4 aR, aZ, aX, aN;
            aR = mfma16(wA[0][0], gA0, cbR);  aR = mfma16(wA[0][1], gA1, aR);
            aR = mfma16(wH[0][0], B0,  aR);   aR = mfma16(wH[0][1], B1,  aR);
            aZ = mfma16(wA[1][0], gA0, cbZ);  aZ = mfma16(wA[1][1], gA1, aZ);
            aZ = mfma16(wH[1][0], B0,  aZ);   aZ = mfma16(wH[1][1], B1,  aZ);
            aX = mfma16(wA[2][0], gA0, cbNx); aX = mfma16(wA[2][1], gA1, aX);
            aN = mfma16(wH[2][0], B0,  cbNh); aN = mfma16(wH[2][1], B1,  aN);
            #pragma unroll
            for (int r = 0; r < 4; ++r){
                float rg = sigm2(aR[r]);
                float zg = sigm2(aZ[r]);
                float ng = tanh2(aX[r] + rg * aN[r]);
                hS[r] = ng + zg * (hS[r] - ng);
            }
            ui2 own = { cvtpk(hS[0], hS[1]), cvtpk(hS[2], hS[3]) };
            hBq[pa][tau][l] = own;
        }
        __syncthreads();
    }

    // Epilogue: L1 waves compute hB(511) from hA(511) (parity 1) and
    // hB(510) (parity 0), then fold the FC dot-product in registers.
    if (layer == 1){
        ui2 a0 = hAq[1][0][l], a1 = hAq[1][1][l];
        ui2 a2 = hAq[1][2][l], a3 = hAq[1][3][l];
        ui2 c0 = hBq[0][0][l], c1 = hBq[0][1][l];
        ui2 c2 = hBq[0][2][l], c3 = hBq[0][3][l];
        ui4 ua0 = {a0[0], a0[1], a1[0], a1[1]};
        ui4 ua1 = {a2[0], a2[1], a3[0], a3[1]};
        ui4 ub0 = {c0[0], c0[1], c1[0], c1[1]};
        ui4 ub1 = {c2[0], c2[1], c3[0], c3[1]};
        bf16x8 gA0 = __builtin_bit_cast(bf16x8, ua0);
        bf16x8 gA1 = __builtin_bit_cast(bf16x8, ua1);
        bf16x8 B0  = __builtin_bit_cast(bf16x8, ub0);
        bf16x8 B1  = __builtin_bit_cast(bf16x8, ub1);
        f32x4 aR, aZ, aX, aN;
        aR = mfma16(wA[0][0], gA0, cbR);  aR = mfma16(wA[0][1], gA1, aR);
        aR = mfma16(wH[0][0], B0,  aR);   aR = mfma16(wH[0][1], B1,  aR);
        aZ = mfma16(wA[1][0], gA0, cbZ);  aZ = mfma16(wA[1][1], gA1, aZ);
        aZ = mfma16(wH[1][0], B0,  aZ);   aZ = mfma16(wH[1][1], B1,  aZ);
        aX = mfma16(wA[2][0], gA0, cbNx); aX = mfma16(wA[2][1], gA1, aX);
        aN = mfma16(wH[2][0], B0,  cbNh); aN = mfma16(wH[2][1], B1,  aN);
        float part = 0.0f;
        #pragma unroll
        for (int r = 0; r < 4; ++r){
            float rg = sigm2(aR[r]);
            float zg = sigm2(aZ[r]);
            float ng = tanh2(aX[r] + rg * aN[r]);
            float hf = ng + zg * (hS[r] - ng);
            part = fmaf(ld_any(Wfc, hb0 + r, f32), hf, part);
        }
        part += __shfl_xor(part, 16);      // reduce across hp
        part += __shfl_xor(part, 32);
        if (l < 16) fcb[tau][b] = part;
    }
    __syncthreads();

    if (wv == 0 && l < 16){
        float s = fcb[0][b] + fcb[1][b] + fcb[2][b] + fcb[3][b]
                + ld_any(bfc, 0, f32);
        if (f32) ((float*)outv)[row0 + b] = s;
        else     ((ushort_t*)outv)[row0 + b] = f2bf(s);
    }
}

extern "C" void kernel_launch(void* const* d_in, const int* in_sizes, int n_in,
                              void* d_out, int out_size, void* d_ws, size_t ws_size,
                              hipStream_t stream)
{
    (void)in_sizes; (void)n_in; (void)d_ws; (void)ws_size;
    const int B = out_size;               // O = 1 -> out_size == batch
    const int nblk = B / BROWS;           // 2048/16 = 128 blocks, 8 waves each
    gru_fused<<<nblk, 512, 0, stream>>>(
        d_in[0],
        d_in[1], d_in[2], d_in[3], d_in[4],
        d_in[5], d_in[6], d_in[7], d_in[8],
        d_in[9], d_in[10],
        d_out);
}